// Round 9
// baseline (86.027 us; speedup 1.0000x reference)
//
#include <hip/hip_runtime.h>
#include <math.h>

#define NPART 4096
#define NBLK  1024
#define NTHR  512   // 8 waves: 2 waves per own-i
#define IPB   4     // particles (i) per block
#define SMAX  256   // local collision-set cap (expected ~60; own i's pre-seeded)
#define PPT   (NPART / NTHR)   // 8 particles per thread in the mean pass
#define HALF4 (NPART / 2 / 2)  // 1024 float4's per half-range (R8 BUG: was /4/2=512 -> half the particles never swept)

// Constants, rounded exactly as the reference's weak-typed doubles -> f32
constexpr float RORC   = (float)(2.5e-5 + 3.15e-6);    // RO + RC
constexpr float RORC2  = RORC * RORC;
constexpr float RRF    = 8e-6f;
constexpr float RR2    = RRF * RRF;
constexpr float TWORC  = (float)(2.0 * 3.15e-6);
constexpr float TWORC2 = TWORC * TWORC;
constexpr float C21RC  = (float)(2.1 * 3.15e-6);
constexpr float RCAND2 = 1.6e-9f;                      // (4e-5)^2 >= 3-hop chain span
constexpr float C_ROT  = (float)(0.2 * 25.0 * 0.0028);
constexpr float C_RN1  = (float)0.07483314773547883;
constexpr float C_SQDT = (float)0.4472135954999579;
constexpr float C_TRV  = (float)(0.2 * 5e-7);
constexpr float C_HALF = (float)0.7071067811865476;
constexpr float C_SQ2T = (float)1.6733200530681511e-07;
constexpr float EPSF   = 1e-14f;

// ---------------------------------------------------------------------------
// R8 retry with the HALF4 constant fixed (1024, was 512 -> particles
// 2048..4095 unswept -> absmax 5.63). MAX-OCCUPANCY experiment: 512 thr x
// 1024 blk = 8192 waves = 32 waves/CU (HW max; LDS 8.5KB, VGPR ~20), two
// waves per own-i each sweeping HALF the j-range (16 iters) -> per-wave
// critical path halved; halves combined with one add at epilogue read.
// Decision: <=81 -> continue this axis; >=82.5 -> declare practical ceiling.
// ---------------------------------------------------------------------------
__global__ __launch_bounds__(NTHR, 8) void fused_all(
        const float2* __restrict__ pos, const float2* __restrict__ ori,
        const float* __restrict__ Deltas, const float* __restrict__ rot_noise,
        const float2* __restrict__ trans_noise, float2* __restrict__ out) {
    __shared__ float    sred[2 * NTHR];       // 4 KB mean tree
    __shared__ float    resW[5][8];           // per-wave partials
    __shared__ unsigned bmap[NPART / 32];     // 512 B dedup table
    __shared__ int      Sidx[SMAX];           // 1 KB
    __shared__ float4   posS4[SMAX / 2];      // 2 KB
    __shared__ int      scnt;
    float2* posS = (float2*)posS4;
    const float4* __restrict__ pos4 = (const float4*)pos;

    const int tid  = threadIdx.x;
    const int w    = tid >> 6;            // wave 0..7
    const int il   = w >> 1;              // own-i 0..3 (two waves each)
    const int h    = w & 1;               // which half of j-range
    const int lane = tid & 63;
    const int base = blockIdx.x * IPB;
    const int gi   = base + il;

    // ---- entry: issue every cold load now; warm scattered-read arrays ----
    const float2 pi   = pos[gi];
    const float  delv = Deltas[0];
    float rn_early = 0.f;
    if (tid < IPB) rn_early = rot_noise[base + tid];
    {   // one float2 per thread at stride 8 covers all 32KB of each array
        const float2 ow = ori[tid * 8];
        const float2 tw = trans_noise[tid * 8];
        asm volatile("" :: "v"(ow.x), "v"(ow.y), "v"(tw.x), "v"(tw.y));
    }

    if (tid == 0) scnt = IPB;             // slots 0..3 = own i's
    if (tid < IPB) Sidx[tid] = base + tid;
    if (tid < NPART / 32) {               // zero + pre-seed own-i bits
        const int seedw = base >> 5;      // all 4 own i's share one word
        bmap[tid] = (tid == seedw) ? (0xFu << (base & 31)) : 0u;
    }

    // ---- mean partials (8 per thread; also warms pos) ----
    float mx = 0.f, my = 0.f;
    #pragma unroll
    for (int k = 0; k < PPT; ++k) {
        const float2 v = pos[k * NTHR + tid];
        mx += v.x; my += v.y;
    }
    sred[tid] = mx; sred[NTHR + tid] = my;
    __syncthreads();                      // #1: bmap/scnt/Sidx/sred ready

    // ---- A. sweep: TWO waves per own-i, each over half the j-range ----
    float nr = 0.f, sx = 0.f, sy = 0.f, oxs = 0.f, oys = 0.f;
    #pragma unroll 2
    for (int t = h * HALF4 + lane; t < (h + 1) * HALF4; t += 64) {
        const float4 wv = pos4[t];
        const float dx0 = wv.x - pi.x, dy0 = wv.y - pi.y;
        const float r20 = fmaf(dx0, dx0, dy0 * dy0);
        const float dx1 = wv.z - pi.x, dy1 = wv.w - pi.y;
        const float r21 = fmaf(dx1, dx1, dy1 * dy1);
        if (fminf(r20, r21) > RCAND2) continue;   // exact both-fail skip
        if (r20 <= RCAND2) {
            const int j = 2 * t;
            const unsigned bit = 1u << (j & 31);
            const unsigned old = atomicOr(&bmap[j >> 5], bit);
            if (!(old & bit)) {                   // first discoverer appends
                const int slot = atomicAdd(&scnt, 1);
                if (slot < SMAX) Sidx[slot] = j;
            }
            if (r20 <= RORC2) {           // inside_Ro
                const float2 uj = ori[j];
                oxs += uj.x; oys += uj.y;
                if (r20 <= RR2 && r20 > 0.f) {
                    // in_front fails <=> dot<=0 && cross>=0
                    const float dt_ = fmaf(dx0, uj.x, dy0 * uj.y);
                    const float cr_ = fmaf(dy0, uj.x, -dx0 * uj.y);
                    if (!((dt_ <= 0.f) && (cr_ >= 0.f))) {
                        nr += 1.f; sx += wv.x; sy += wv.y;
                    }
                }
            }
        }
        if (r21 <= RCAND2) {
            const int j = 2 * t + 1;
            const unsigned bit = 1u << (j & 31);
            const unsigned old = atomicOr(&bmap[j >> 5], bit);
            if (!(old & bit)) {
                const int slot = atomicAdd(&scnt, 1);
                if (slot < SMAX) Sidx[slot] = j;
            }
            if (r21 <= RORC2) {
                const float2 uj = ori[j];
                oxs += uj.x; oys += uj.y;
                if (r21 <= RR2 && r21 > 0.f) {
                    const float dt_ = fmaf(dx1, uj.x, dy1 * uj.y);
                    const float cr_ = fmaf(dy1, uj.x, -dx1 * uj.y);
                    if (!((dt_ <= 0.f) && (cr_ >= 0.f))) {
                        nr += 1.f; sx += wv.z; sy += wv.w;
                    }
                }
            }
        }
    }
    {   // 64-lane shuffle reduction -> per-wave partial slot
        float vals[5] = {nr, sx, sy, oxs, oys};
        #pragma unroll
        for (int q = 0; q < 5; ++q)
            #pragma unroll
            for (int off = 32; off >= 1; off >>= 1)
                vals[q] += __shfl_down(vals[q], off);
        if (lane == 0) {
            resW[0][w] = vals[0]; resW[1][w] = vals[1]; resW[2][w] = vals[2];
            resW[3][w] = vals[3]; resW[4][w] = vals[4];
        }
    }
    __syncthreads();                      // #2: resW/scnt/Sidx/bmap final

    // ---- tree s=256 + D1 translate (scattered reads L2-warm) ----
    const int nS = (scnt < SMAX) ? scnt : SMAX;
    if (tid < 256) {
        sred[tid]        += sred[tid + 256];
        sred[NTHR + tid] += sred[NTHR + tid + 256];
    }
    if (tid < nS) {
        const int p = Sidx[tid];
        const float2 pq = pos[p];
        const float2 uu = ori[p];
        const float2 tn = trans_noise[p];
        posS[tid] = make_float2(
            pq.x + (C_TRV * uu.x + ((tn.x * C_HALF) * C_SQ2T) * C_SQDT),
            pq.y + (C_TRV * uu.y + ((tn.y * C_HALF) * C_SQ2T) * C_SQDT));
    }
    __syncthreads();                      // #3: s=256 done; posS complete

    if (tid < 128) {
        sred[tid]        += sred[tid + 128];
        sred[NTHR + tid] += sred[NTHR + tid + 128];
    }
    __syncthreads();                      // #4: s=128 done (128 entries left)

    // ---- tree s<=64 in wave 0 (s=64 per-lane add, then shuffle ladder:
    //      identical pairwise association to the LDS ladder) ----
    float cmx = 0.f, cmy = 0.f;
    if (w == 0) {
        float vx = sred[lane]        + sred[lane + 64];          // s=64 step
        float vy = sred[NTHR + lane] + sred[NTHR + lane + 64];
        #pragma unroll
        for (int off = 32; off >= 1; off >>= 1) {
            vx += __shfl_down(vx, off);
            vy += __shfl_down(vy, off);
        }
        cmx = __shfl(vx, 0) * (1.f / NPART);
        cmy = __shfl(vy, 0) * (1.f / NPART);
    }

    // ---- C2. per-i epilogue (4 threads = lanes 0..3 of wave 0);
    //      half-sweep partials combined here with one add ----
    if (tid < IPB) {
        const int g2 = base + tid;
        const float2 p = pos[g2];
        const float2 u = ori[g2];
        const int wa = 2 * tid, wb = 2 * tid + 1;
        const float nrv = resW[0][wa] + resW[0][wb];
        const float sxv = resW[1][wa] + resW[1][wb];
        const float syv = resW[2][wa] + resW[2][wb];
        const float osx = resW[3][wa] + resW[3][wb];
        const float osy = resW[4][wa] + resW[4][wb];

        const float inv = 1.f / fmaxf(nrv, 1.f);
        const float sg  = (nrv > 0.f) ? 1.f : 0.f;
        const float Sx = sxv * inv - p.x * sg;
        const float Sy = syv * inv - p.y * sg;
        const float dxv = -Sx, dyv = -Sy;        // d = -S

        const float Psx = cmx - p.x;
        const float Psy = cmy - p.y;

        float sd, cd;
        sincosf(delv, &sd, &cd);
        const float Lx = Psx * cd - Psy * sd;    // Ps * exp(+i*Delta)
        const float Ly = Psx * sd + Psy * cd;
        const float Rx = Psx * cd + Psy * sd;    // Ps * exp(-i*Delta)
        const float Ry = Psy * cd - Psx * sd;

        const float no  = fmaxf(sqrtf(osx * osx + osy * osy + 1e-30f), EPSF);
        const float nl  = fmaxf(sqrtf(Lx * Lx + Ly * Ly + 1e-30f), EPSF);
        const float nrr = fmaxf(sqrtf(Rx * Rx + Ry * Ry + 1e-30f), EPSF);
        const float csl = (Lx * osx + Ly * osy) / (nl * no);
        const float csr = (Rx * osx + Ry * osy) / (nrr * no);
        const bool left = (csl >= csr);
        const float bx = left ? Lx : Rx;
        const float by = left ? Ly : Ry;

        float cx, cy;
        if (dxv != 0.f || dyv != 0.f)    { cx = dxv; cy = dyv; }
        else if (bx != 0.f || by != 0.f) { cx = bx;  cy = by;  }
        else                             { cx = 1.f; cy = 0.f; }

        const float dt_ = cx * u.x + cy * u.y;
        const float cr_ = cy * u.x - cx * u.y;
        const float sin_t = cr_ / sqrtf(dt_ * dt_ + cr_ * cr_);

        const float ang = C_ROT * sin_t + (rn_early * C_RN1) * C_SQDT;
        float sa, ca;
        sincosf(ang, &sa, &ca);
        out[1 * NPART + g2] = make_float2(u.x * ca - u.y * sa,
                                          u.x * sa + u.y * ca);
        out[2 * NPART + g2] = make_float2(osx, osy);
        out[3 * NPART + g2] = make_float2(Lx, Ly);
        out[4 * NPART + g2] = make_float2(Rx, Ry);
    }

    // ---- D2. three local JACOBI passes over S (nS <= 256 < NTHR) ----
    for (int pass = 0; pass < 3; ++pass) {
        float px = 1e9f, py = 1e9f, ax = 0.f, ay = 0.f;
        const bool mv = (tid < nS);
        if (mv) { px = posS[tid].x; py = posS[tid].y; }
        int b = 0;
        for (; b + 4 <= nS; b += 4) {
            const float4 w0 = posS4[(b >> 1)];
            const float4 w1 = posS4[(b >> 1) + 1];
            const float bxs[4] = {w0.x, w0.z, w1.x, w1.z};
            const float bys[4] = {w0.y, w0.w, w1.y, w1.w};
            #pragma unroll
            for (int s = 0; s < 4; ++s) {
                const float dx = bxs[s] - px, dy = bys[s] - py;
                const float r2 = fmaf(dx, dx, dy * dy);
                if (r2 <= TWORC2 && r2 > 0.f) {
                    const float ab = sqrtf(r2);
                    const float sc = (C21RC - ab) * 0.5f / ab;
                    ax = fmaf(dx, sc, ax);
                    ay = fmaf(dy, sc, ay);
                }
            }
        }
        for (; b < nS; ++b) {
            const float2 pb = posS[b];
            const float dx = pb.x - px, dy = pb.y - py;
            const float r2 = fmaf(dx, dx, dy * dy);
            if (r2 <= TWORC2 && r2 > 0.f) {
                const float ab = sqrtf(r2);
                const float sc = (C21RC - ab) * 0.5f / ab;
                ax = fmaf(dx, sc, ax);
                ay = fmaf(dy, sc, ay);
            }
        }
        __syncthreads();                  // all reads done (Jacobi)
        if (mv) posS[tid] = make_float2(px - ax, py - ay);
        __syncthreads();
    }
    // ---- section 0: own 4 i's are slots 0..3 of S ----
    if (tid < IPB)
        out[0 * NPART + base + tid] = posS[tid];
}

extern "C" void kernel_launch(void* const* d_in, const int* in_sizes, int n_in,
                              void* d_out, int out_size, void* d_ws, size_t ws_size,
                              hipStream_t stream) {
    const float2* pos = (const float2*)d_in[0];
    const float2* ori = (const float2*)d_in[1];
    const float*  del = (const float*)d_in[2];
    const float*  rn  = (const float*)d_in[3];
    const float2* tn  = (const float2*)d_in[4];
    float2* o2 = (float2*)d_out;          // [5][N] float2
    (void)d_ws; (void)ws_size;

    fused_all<<<dim3(NBLK), dim3(NTHR), 0, stream>>>(pos, ori, del, rn, tn, o2);
}